// Round 2
// baseline (694.697 us; speedup 1.0000x reference)
//
#include <hip/hip_runtime.h>
#include <math.h>

#define NK   21
#define TILE 64
#define HALO 4
#define IN_W (TILE + 2*HALO)   // 72
#define HW   512

typedef float f32x4 __attribute__((ext_vector_type(4)));

struct GParams {
    float g[NK][5];   // g[i][d] = weight at distance d (0..R), 0 beyond
    int   R[NK];      // effective radius, 1..4
};

__device__ __forceinline__ int refl(int v) {
    v = (v < 0) ? -v : v;
    return (v > HW - 1) ? (2 * (HW - 1) - v) : v;
}

// Vertical pass: sIn (72x72) -> sScr (64x72). Tasks: 8 row-groups x 72 cols.
// Each task computes 8 consecutive output rows in one column via a register window.
template<int R>
__device__ __forceinline__ void vpass(const float* sIn, float* sScr,
                                      const float g[5], int tid) {
    constexpr int WIN = 8 + 2 * R;
    for (int t = tid; t < 8 * IN_W; t += 256) {
        int rg = t / IN_W;
        int c  = t - rg * IN_W;
        const float* src = sIn + (8 * rg + HALO - R) * IN_W + c;
        float win[WIN];
        #pragma unroll
        for (int j = 0; j < WIN; ++j) win[j] = src[j * IN_W];
        float* dst = sScr + (8 * rg) * IN_W + c;
        #pragma unroll
        for (int s = 0; s < 8; ++s) {
            float acc = g[0] * win[s + R];
            #pragma unroll
            for (int d = 1; d <= R; ++d)
                acc += g[d] * (win[s + R - d] + win[s + R + d]);
            dst[s * IN_W] = acc;
        }
    }
}

// Horizontal pass: sScr (64x72, col c == global x0-4+c) -> global out plane.
// Tasks: 64 rows x 8 col-groups of 8. Window = 16 contiguous floats (4x b128).
template<int R>
__device__ __forceinline__ void hpass(const float* sScr, float* op,
                                      const float g[5], int tid, int y0, int x0) {
    for (int t = tid; t < 512; t += 256) {
        int r  = t >> 3;
        int w0 = (t & 7) << 3;
        const f32x4* rp = (const f32x4*)(sScr + r * IN_W + w0);
        f32x4 A = rp[0], B = rp[1], C = rp[2], D = rp[3];
        float win[16] = {A.x, A.y, A.z, A.w, B.x, B.y, B.z, B.w,
                         C.x, C.y, C.z, C.w, D.x, D.y, D.z, D.w};
        float o[8];
        #pragma unroll
        for (int u = 0; u < 8; ++u) {
            float acc = g[0] * win[u + 4];
            #pragma unroll
            for (int d = 1; d <= R; ++d)
                acc += g[d] * (win[u + 4 - d] + win[u + 4 + d]);
            o[u] = acc;
        }
        float* po = op + (y0 + r) * HW + x0 + w0;
        f32x4 v0 = {o[0], o[1], o[2], o[3]};
        f32x4 v1 = {o[4], o[5], o[6], o[7]};
        __builtin_nontemporal_store(v0, (f32x4*)po);
        __builtin_nontemporal_store(v1, (f32x4*)po + 1);
    }
}

__global__ __launch_bounds__(256, 4)
void gauss_all(const float* __restrict__ x, float* __restrict__ out, GParams P) {
    __shared__ float sIn[IN_W * IN_W];   // 20.25 KB
    __shared__ float sScr[TILE * IN_W];  // 18 KB
    const int tid   = threadIdx.x;
    const int bid   = blockIdx.x;
    const int plane = bid >> 6;          // 0..23  (b*3 + c)
    const int tile  = bid & 63;
    const int bb = plane / 3, cc = plane - 3 * bb;
    const int y0 = (tile >> 3) << 6;
    const int x0 = (tile & 7) << 6;
    const float* ip = x + (size_t)plane * (HW * HW);

    // stage reflect-padded 72x72 input tile
    for (int t = tid; t < IN_W * IN_W; t += 256) {
        int ir = t / IN_W;
        int ic = t - ir * IN_W;
        sIn[t] = ip[refl(y0 - HALO + ir) * HW + refl(x0 - HALO + ic)];
    }
    __syncthreads();

    // identity channel (out channel bb*66 + cc)
    {
        float* op = out + (size_t)(bb * 66 + cc) * (HW * HW);
        for (int t = tid; t < 1024; t += 256) {
            int r = t >> 4, w4 = (t & 15) << 2;
            f32x4 v = *(const f32x4*)(sIn + (HALO + r) * IN_W + HALO + w4);
            __builtin_nontemporal_store(v, (f32x4*)(op + (y0 + r) * HW + x0 + w4));
        }
    }

    #pragma unroll 1
    for (int i = 0; i < NK; ++i) {
        float g[5];
        #pragma unroll
        for (int d = 0; d < 5; ++d) g[d] = P.g[i][d];
        float* op = out + (size_t)(bb * 66 + 3 + 3 * i + cc) * (HW * HW);
        switch (P.R[i]) {
            case 1: vpass<1>(sIn, sScr, g, tid); __syncthreads();
                    hpass<1>(sScr, op, g, tid, y0, x0); break;
            case 2: vpass<2>(sIn, sScr, g, tid); __syncthreads();
                    hpass<2>(sScr, op, g, tid, y0, x0); break;
            case 3: vpass<3>(sIn, sScr, g, tid); __syncthreads();
                    hpass<3>(sScr, op, g, tid, y0, x0); break;
            default: vpass<4>(sIn, sScr, g, tid); __syncthreads();
                    hpass<4>(sScr, op, g, tid, y0, x0); break;
        }
        __syncthreads();
    }
}

static GParams make_params() {
    GParams P;
    const double inc = 18.0 / 19.0;   // (MAX-INIT)/(NUM-2), replicate Python doubles
    for (int i = 0; i < NK; ++i) {
        double f1 = (double)i * inc;
        double f3 = floor(f1 / 2.0) * 2.0;
        int ks = (int)(3.0 + f3);
        if (ks > 21) ks = 21;
        int p = (ks - 1) / 2;
        double sig = 0.5 + 0.025 * (double)i;
        double s2  = 2.0 * sig * sig;
        double S = 0.0;
        for (int m = -p; m <= p; ++m) S += exp(-(double)(m * m) / s2);
        // minimal R with dropped tail mass <= 3e-4 (per axis), capped at 4
        int R = p;
        for (int r = 1; r <= p; ++r) {
            double Sr = 0.0;
            for (int m = -r; m <= r; ++m) Sr += exp(-(double)(m * m) / s2);
            if ((S - Sr) / S <= 3e-4) { R = r; break; }
        }
        if (R > 4) R = 4;
        P.R[i] = R;
        for (int d = 0; d < 5; ++d)
            P.g[i][d] = (d <= R) ? (float)(exp(-(double)(d * d) / s2) / S) : 0.0f;
    }
    return P;
}

extern "C" void kernel_launch(void* const* d_in, const int* in_sizes, int n_in,
                              void* d_out, int out_size, void* d_ws, size_t ws_size,
                              hipStream_t stream) {
    const float* x = (const float*)d_in[0];
    float* out = (float*)d_out;
    GParams P = make_params();   // cheap host math, identical every call
    gauss_all<<<dim3(24 * 64), dim3(256), 0, stream>>>(x, out, P);
}